// Round 4
// baseline (23606.848 us; speedup 1.0000x reference)
//
#include <hip/hip_runtime.h>
#include <hip/hip_bf16.h>
#include <stdint.h>

// Bi-LSTM (H=1024, bidirectional, H2=512) + linear head + CRF Viterbi decode.
// Strategy:
//  K1 lstm_init     : zero sync counters, publish h0 into h-exchange buffer
//  K2 xproj_gemm    : xproj[dir][t][g] = embed[sent[t]] . Wih_dir[g] + bih+bhh   (f32 tiled GEMM, gather fused)
//  K3 lstm_kernel   : 32 WGs/direction, Whh slice in VGPRs, per-step global h exchange
//                     via agent-scope atomics + release/acquire counter barrier.
//                     Spin-wait is BUDGETED (2^23 total iters/WG) so a sync failure
//                     degrades to a wrong answer, never a GPU hang.
//  K4 feats_kernel  : feats[t][j] = [hf|hb][t] . W_out[j] + b_out[j]
//  K5 viterbi_kernel: 12-tag max-plus DP in one wave, backpointers in LDS, backtrack
// All f32 end-to-end (best_path must match the numpy reference argmax decisions).

#define S_LEN 4096
#define DIM   1024
#define H2    512
#define G4    2048
#define NTAG  12
#define START_TAG 10
#define STOP_TAG  11
#define NEGV  (-10000.0f)
#define WGS_PER_DIR 32

// ---------------------------------------------------------------- xproj GEMM
#define BM 128
#define BN 128
#define BK 16

__global__ __launch_bounds__(256) void xproj_gemm(
    const int* __restrict__ sent, const float* __restrict__ embed,
    const float* __restrict__ Wih_f, const float* __restrict__ bih_f, const float* __restrict__ bhh_f,
    const float* __restrict__ Wih_b, const float* __restrict__ bih_b, const float* __restrict__ bhh_b,
    float* __restrict__ xproj_f, float* __restrict__ xproj_b)
{
    const int dir = blockIdx.z;
    const float* W  = dir ? Wih_b : Wih_f;
    const float* b1 = dir ? bih_b : bih_f;
    const float* b2 = dir ? bhh_b : bhh_f;
    float* out = dir ? xproj_b : xproj_f;
    const int m0 = blockIdx.y * BM;
    const int n0 = blockIdx.x * BN;

    __shared__ __align__(16) float As[BK][BM + 4];   // stored transposed: As[k][m]
    __shared__ __align__(16) float Bs[BK][BN + 4];   // Bs[k][n]
    __shared__ int rowsh[BM];

    const int tid = threadIdx.x;
    if (tid < BM) rowsh[tid] = sent[m0 + tid];
    __syncthreads();

    const int tx = tid & 15, ty = tid >> 4;
    float acc[8][8];
    #pragma unroll
    for (int i = 0; i < 8; i++)
        #pragma unroll
        for (int j = 0; j < 8; j++) acc[i][j] = 0.f;

    for (int k0 = 0; k0 < DIM; k0 += BK) {
        #pragma unroll
        for (int l = 0; l < 2; l++) {
            const int id = tid + l * 256;        // 0..511
            const int r  = id >> 2;              // row 0..127
            const int kc = (id & 3) << 2;        // k chunk 0,4,8,12
            const float4 va = *(const float4*)(embed + (size_t)rowsh[r] * DIM + k0 + kc);
            As[kc + 0][r] = va.x; As[kc + 1][r] = va.y; As[kc + 2][r] = va.z; As[kc + 3][r] = va.w;
            const float4 vb = *(const float4*)(W + (size_t)(n0 + r) * DIM + k0 + kc);
            Bs[kc + 0][r] = vb.x; Bs[kc + 1][r] = vb.y; Bs[kc + 2][r] = vb.z; Bs[kc + 3][r] = vb.w;
        }
        __syncthreads();
        #pragma unroll
        for (int k = 0; k < BK; k++) {
            float a[8], bb[8];
            *(float4*)&a[0]  = *(const float4*)&As[k][ty * 8];
            *(float4*)&a[4]  = *(const float4*)&As[k][ty * 8 + 4];
            *(float4*)&bb[0] = *(const float4*)&Bs[k][tx * 8];
            *(float4*)&bb[4] = *(const float4*)&Bs[k][tx * 8 + 4];
            #pragma unroll
            for (int i = 0; i < 8; i++)
                #pragma unroll
                for (int j = 0; j < 8; j++)
                    acc[i][j] += a[i] * bb[j];
        }
        __syncthreads();
    }

    #pragma unroll
    for (int i = 0; i < 8; i++) {
        const size_t trow = (size_t)(m0 + ty * 8 + i) * G4;
        #pragma unroll
        for (int j = 0; j < 8; j += 4) {
            const int n = n0 + tx * 8 + j;
            float4 v;
            v.x = acc[i][j + 0] + b1[n + 0] + b2[n + 0];
            v.y = acc[i][j + 1] + b1[n + 1] + b2[n + 1];
            v.z = acc[i][j + 2] + b1[n + 2] + b2[n + 2];
            v.w = acc[i][j + 3] + b1[n + 3] + b2[n + 3];
            *(float4*)(out + trow + n) = v;
        }
    }
}

// ---------------------------------------------------------------- init
__global__ __launch_bounds__(256) void lstm_init(
    const float* __restrict__ h0, float* __restrict__ hbuf, unsigned int* __restrict__ cnt)
{
    const int tid = threadIdx.x;
    // zero per-step arrival counters (ws is poisoned 0xAA before every launch)
    for (int i = tid; i < 2 * (S_LEN + 1); i += 256) cnt[i] = 0;
    // hbuf layout: [dir][2][H2]; buffer 0 holds h_{t=0} = h0[dir]
    for (int i = tid; i < 2 * H2; i += 256) {
        const int dir = i >> 9, u = i & (H2 - 1);
        hbuf[dir * (2 * H2) + u] = h0[i];
    }
    // step 0 is "complete" (same thread zeroed these slots above -> ordered)
    if (tid < 2) cnt[tid * (S_LEN + 1)] = WGS_PER_DIR;
}

// ---------------------------------------------------------------- LSTM recurrence
// 64 blocks x 256 threads. Block wg: dir = wg>>5, unit slice = (wg&31)*16 .. +15.
// Wave v (4 waves) owns units U0+4v..U0+4v+3; 16 gate rows/wave (4 units x 4 gates).
// Lane l holds Whh[row][4l..4l+3] and Whh[row][256+4l..256+4l+3] in VGPRs.
__global__ __launch_bounds__(256, 1) void lstm_kernel(
    const float* __restrict__ Whh_f, const float* __restrict__ Whh_b,
    const float* __restrict__ c0,
    const float* __restrict__ xproj_f, const float* __restrict__ xproj_b,
    float* __restrict__ hseq_f, float* __restrict__ hseq_b,
    float* hbuf, unsigned int* cnt)
{
    const int wg   = blockIdx.x;
    const int dir  = wg >> 5;
    const int U0   = (wg & 31) * 16;
    const float* Whh   = dir ? Whh_b   : Whh_f;
    const float* xproj = dir ? xproj_b : xproj_f;
    float* hseq        = dir ? hseq_b  : hseq_f;
    float* hb          = hbuf + dir * (2 * H2);
    unsigned int* cn   = cnt + dir * (S_LEN + 1);

    const int tid  = threadIdx.x;
    const int wave = tid >> 6;
    const int lane = tid & 63;

    __shared__ __align__(16) float hsh[H2];
    __shared__ __align__(16) float red[4][16][68];   // [wave][row][lane], padded rows

    float4 wlo[16], whi[16];
    #pragma unroll
    for (int r = 0; r < 16; r++) {
        const int up = r >> 2, g = r & 3;
        const int row = g * H2 + U0 + wave * 4 + up;
        wlo[r] = *(const float4*)(Whh + (size_t)row * H2 + 4 * lane);
        whi[r] = *(const float4*)(Whh + (size_t)row * H2 + 256 + 4 * lane);
    }

    const int myunit = U0 + wave * 4 + (lane & 3);
    float cstate = (lane < 4) ? c0[dir * H2 + myunit] : 0.f;

    // Cumulative spin budget: normal total ~5e4 iters; 2^23 = ~150x headroom.
    // On exhaustion we proceed (wrong answer, but the GPU NEVER hangs).
    int spin_budget = 1 << 23;

    for (int t = 1; t <= S_LEN; t++) {
        const int sidx = dir ? (S_LEN - t) : (t - 1);

        // prefetch this step's input-projection gates (no cross-WG dependency)
        float xp0 = 0.f, xp1 = 0.f, xp2 = 0.f, xp3 = 0.f;
        if (lane < 4) {
            const float* xr = xproj + (size_t)sidx * G4 + myunit;
            xp0 = xr[0]; xp1 = xr[H2]; xp2 = xr[2 * H2]; xp3 = xr[3 * H2];
        }

        // wait for all 32 WGs of this direction to publish h_{t-1}
        // (relaxed spin; the agent-acquire fence below pairs with the
        //  producers' release fetch_add)
        if (tid == 0) {
            while (__hip_atomic_load(&cn[t - 1], __ATOMIC_RELAXED, __HIP_MEMORY_SCOPE_AGENT)
                   != WGS_PER_DIR) {
                if (--spin_budget < 0) break;
                __builtin_amdgcn_s_sleep(2);
            }
        }
        __syncthreads();
        __builtin_amdgcn_fence(__ATOMIC_ACQUIRE, "agent");

        {   // stage h_{t-1} (coherent loads) into LDS
            const int pb = (t - 1) & 1;
            hsh[tid]       = __hip_atomic_load(&hb[pb * H2 + tid],       __ATOMIC_RELAXED, __HIP_MEMORY_SCOPE_AGENT);
            hsh[256 + tid] = __hip_atomic_load(&hb[pb * H2 + 256 + tid], __ATOMIC_RELAXED, __HIP_MEMORY_SCOPE_AGENT);
        }
        __syncthreads();

        const float4 hlo = *(const float4*)&hsh[4 * lane];
        const float4 hhi = *(const float4*)&hsh[256 + 4 * lane];
        #pragma unroll
        for (int r = 0; r < 16; r++) {
            const float s = wlo[r].x * hlo.x + wlo[r].y * hlo.y + wlo[r].z * hlo.z + wlo[r].w * hlo.w
                          + whi[r].x * hhi.x + whi[r].y * hhi.y + whi[r].z * hhi.z + whi[r].w * hhi.w;
            red[wave][r][lane] = s;
        }
        __syncthreads();

        // lane l sums quarter (l>>4) of row (l&15), then folds quarters across lanes
        const float* rp = &red[wave][lane & 15][(lane >> 4) * 16];
        const float4 q0 = *(const float4*)(rp);
        const float4 q1 = *(const float4*)(rp + 4);
        const float4 q2 = *(const float4*)(rp + 8);
        const float4 q3 = *(const float4*)(rp + 12);
        float ssum = ((q0.x + q0.y) + (q0.z + q0.w)) + ((q1.x + q1.y) + (q1.z + q1.w))
                   + ((q2.x + q2.y) + (q2.z + q2.w)) + ((q3.x + q3.y) + (q3.z + q3.w));
        ssum += __shfl_xor(ssum, 16);
        ssum += __shfl_xor(ssum, 32);
        // row (lane&15) total now in ssum; gather this unit's 4 gates
        const int fb = 4 * (lane & 3);
        const float gi = __shfl(ssum, fb + 0);
        const float gf = __shfl(ssum, fb + 1);
        const float gg = __shfl(ssum, fb + 2);
        const float go = __shfl(ssum, fb + 3);

        if (lane < 4) {
            const float pi = gi + xp0;
            const float pf = gf + xp1;
            const float pg = gg + xp2;
            const float po = go + xp3;
            const float i_ = 1.f / (1.f + expf(-pi));
            const float f_ = 1.f / (1.f + expf(-pf));
            const float g_ = tanhf(pg);
            const float o_ = 1.f / (1.f + expf(-po));
            cstate = f_ * cstate + i_ * g_;
            const float hnew = o_ * tanhf(cstate);
            hseq[(size_t)sidx * H2 + myunit] = hnew;
            __hip_atomic_store(&hb[(t & 1) * H2 + myunit], hnew,
                               __ATOMIC_RELAXED, __HIP_MEMORY_SCOPE_AGENT);
        }
        __syncthreads();   // all lanes' h stores drained before the WG arrives
        if (tid == 0)
            (void)__hip_atomic_fetch_add(&cn[t], 1u, __ATOMIC_RELEASE, __HIP_MEMORY_SCOPE_AGENT);
    }
}

// ---------------------------------------------------------------- feats GEMV
__global__ __launch_bounds__(256) void feats_kernel(
    const float* __restrict__ hseq_f, const float* __restrict__ hseq_b,
    const float* __restrict__ W_out, const float* __restrict__ b_out,
    float* __restrict__ feats)
{
    const int wave = threadIdx.x >> 6;
    const int lane = threadIdx.x & 63;
    const int t = blockIdx.x * 4 + wave;
    const float* hf = hseq_f + (size_t)t * H2;
    const float* hb = hseq_b + (size_t)t * H2;
    float h[16];
    #pragma unroll
    for (int i = 0; i < 8; i++) h[i]     = hf[lane + 64 * i];
    #pragma unroll
    for (int i = 0; i < 8; i++) h[8 + i] = hb[lane + 64 * i];
    #pragma unroll
    for (int j = 0; j < NTAG; j++) {
        const float* w = W_out + (size_t)j * DIM;
        float a = 0.f;
        #pragma unroll
        for (int i = 0; i < 8; i++) a += h[i]     * w[lane + 64 * i];
        #pragma unroll
        for (int i = 0; i < 8; i++) a += h[8 + i] * w[512 + lane + 64 * i];
        a += __shfl_xor(a, 1);  a += __shfl_xor(a, 2);  a += __shfl_xor(a, 4);
        a += __shfl_xor(a, 8);  a += __shfl_xor(a, 16); a += __shfl_xor(a, 32);
        if (lane == j) feats[(size_t)t * NTAG + j] = a + b_out[j];
    }
}

// ---------------------------------------------------------------- Viterbi
__global__ __launch_bounds__(64) void viterbi_kernel(
    const float* __restrict__ feats, const float* __restrict__ trans,
    float* __restrict__ out)
{
    __shared__ unsigned char bp[S_LEN][NTAG];    // 48 KB backpointers
    const int lane = threadIdx.x;
    const bool act = lane < NTAG;

    float fv = (lane == START_TAG) ? 0.f : NEGV;
    float tr[NTAG];
    #pragma unroll
    for (int p = 0; p < NTAG; p++) tr[p] = act ? trans[lane * NTAG + p] : NEGV;

    float fq[8];
    #pragma unroll
    for (int i = 0; i < 8; i++) fq[i] = act ? feats[i * NTAG + lane] : 0.f;

    for (int s0 = 0; s0 < S_LEN; s0 += 8) {
        float fn[8];
        #pragma unroll
        for (int i = 0; i < 8; i++) {          // prefetch next 8 steps' feats
            const int sn = s0 + 8 + i;
            fn[i] = (act && sn < S_LEN) ? feats[sn * NTAG + lane] : 0.f;
        }
        #pragma unroll
        for (int i = 0; i < 8; i++) {
            const int s = s0 + i;
            float best = -3.0e38f;
            int bidx = 0;
            #pragma unroll
            for (int p = 0; p < NTAG; p++) {   // strict > keeps FIRST max (np.argmax)
                const float sc = __shfl(fv, p) + tr[p];
                const bool gt = sc > best;
                best = gt ? sc : best;
                bidx = gt ? p : bidx;
            }
            if (act) bp[s][lane] = (unsigned char)bidx;
            fv = best + fq[i];
        }
        #pragma unroll
        for (int i = 0; i < 8; i++) fq[i] = fn[i];
    }

    float bv = act ? (fv + trans[STOP_TAG * NTAG + lane]) : -3.0e38f;
    int bi = lane;
    #pragma unroll
    for (int m = 1; m < 16; m <<= 1) {         // first-max argmax across tags
        const float ov = __shfl_xor(bv, m);
        const int   oi = __shfl_xor(bi, m);
        const bool take = (ov > bv) || (ov == bv && oi < bi);
        bv = take ? ov : bv;
        bi = take ? oi : bi;
    }
    if (lane == 0) {
        out[0] = bv;                            // path_score
        int cur = bi;
        out[1 + S_LEN - 1] = (float)cur;        // best_path[S-1] = best tag
        for (int s = S_LEN - 1; s >= 1; s--) {  // best_path[s-1] = bp[s][tag_{s+1}]
            cur = bp[s][cur];
            out[s] = (float)cur;
        }
    }
}

// ---------------------------------------------------------------- launch
extern "C" void kernel_launch(void* const* d_in, const int* in_sizes, int n_in,
                              void* d_out, int out_size, void* d_ws, size_t ws_size,
                              hipStream_t stream)
{
    const int*   sent  = (const int*)  d_in[0];
    const float* embed = (const float*)d_in[1];
    const float* Wih_f = (const float*)d_in[2];
    const float* Whh_f = (const float*)d_in[3];
    const float* bih_f = (const float*)d_in[4];
    const float* bhh_f = (const float*)d_in[5];
    const float* Wih_b = (const float*)d_in[6];
    const float* Whh_b = (const float*)d_in[7];
    const float* bih_b = (const float*)d_in[8];
    const float* bhh_b = (const float*)d_in[9];
    const float* h0    = (const float*)d_in[10];
    const float* c0    = (const float*)d_in[11];
    const float* W_out = (const float*)d_in[12];
    const float* b_out = (const float*)d_in[13];
    const float* trans = (const float*)d_in[14];
    float* out = (float*)d_out;

    // workspace carve-up (~84.2 MB)
    const size_t n_xproj = (size_t)S_LEN * G4;       // per direction
    const size_t n_hseq  = (size_t)S_LEN * H2;       // per direction
    const size_t n_feats = (size_t)S_LEN * NTAG;
    const size_t needed_floats = 2 * n_xproj + 2 * n_hseq + n_feats
                               + 2 * (2 * H2) + (2 * (S_LEN + 1) + 64);
    if (ws_size < needed_floats * sizeof(float)) {
        // Workspace too small: bail cleanly (out stays memset-0 -> absmax ~1e4
        // signature tells us THIS guard tripped) instead of faulting the GPU.
        return;
    }

    float* xproj_f = (float*)d_ws;
    float* xproj_b = xproj_f + n_xproj;
    float* hseq_f  = xproj_b + n_xproj;
    float* hseq_b  = hseq_f  + n_hseq;
    float* feats   = hseq_b  + n_hseq;
    float* hbuf    = feats   + n_feats;
    unsigned int* cnt = (unsigned int*)(hbuf + 2 * (2 * H2));

    lstm_init<<<1, 256, 0, stream>>>(h0, hbuf, cnt);
    xproj_gemm<<<dim3(G4 / BN, S_LEN / BM, 2), 256, 0, stream>>>(
        sent, embed, Wih_f, bih_f, bhh_f, Wih_b, bih_b, bhh_b, xproj_f, xproj_b);
    lstm_kernel<<<2 * WGS_PER_DIR, 256, 0, stream>>>(
        Whh_f, Whh_b, c0, xproj_f, xproj_b, hseq_f, hseq_b, hbuf, cnt);
    feats_kernel<<<S_LEN / 4, 256, 0, stream>>>(hseq_f, hseq_b, W_out, b_out, feats);
    viterbi_kernel<<<1, 64, 0, stream>>>(feats, trans, out);
}